// Round 1
// baseline (106786.353 us; speedup 1.0000x reference)
//
#include <hip/hip_runtime.h>

// CRF forward-algorithm loss, T=16384, L=1024.
// Strategy: exp-domain recurrence A' = diag(exp(feat)) * W * A  (W = exp(transitions)),
// split into forward half (steps 0..8191) and backward half (steps 16383..8192) that
// run concurrently. Persistent dataflow kernel: 128 fwd + 128 bwd workgroups, each owns
// 8 rows of W (fwd) / 8 cols of W (bwd) in LDS. Per step each wg publishes its 8-entry
// slice (normalized by slice max) + cumulative double log-scale, agent-scope atomics,
// release flag / acquire poll. Double-buffered by step parity.

#define TT   16384
#define LLAB 1024
#define HALF 8192
#define NWG  128   // workgroups per direction
#define RPW  8     // rows (labels) per workgroup
#define CH   20    // padded LDS chunk stride (16 data + 4 pad) -> conflict-free b128 reads

// ---------------- gold path score ----------------
__global__ __launch_bounds__(256) void crf_gold(const float* __restrict__ pred,
                                                const int* __restrict__ ref,
                                                const float* __restrict__ trans,
                                                float* __restrict__ gold) {
  int t = blockIdx.x * 256 + threadIdx.x;           // grid 64 -> one t per thread
  int r = ref[t];
  int prev = (t == 0) ? (LLAB - 2) : ref[t - 1];    // START = L-2
  float v = trans[(size_t)r * LLAB + prev] + pred[(size_t)t * LLAB + r];
  if (t == TT - 1) v += trans[(size_t)(LLAB - 1) * LLAB + r];  // STOP row
#pragma unroll
  for (int off = 32; off >= 1; off >>= 1) v += __shfl_xor(v, off);
  __shared__ float acc[4];
  if ((threadIdx.x & 63) == 0) acc[threadIdx.x >> 6] = v;
  __syncthreads();
  if (threadIdx.x == 0) atomicAdd(gold, acc[0] + acc[1] + acc[2] + acc[3]);
}

// ---------------- persistent dataflow kernel ----------------
__global__ __launch_bounds__(256) void crf_persistent(
    const float* __restrict__ pred, const float* __restrict__ trans,
    int* __restrict__ fwdFlag, int* __restrict__ bwdFlag,
    float* __restrict__ fwdA, float* __restrict__ bwdV,
    double* __restrict__ fwdSc, double* __restrict__ bwdSc) {
  __shared__ float W[RPW][64 * CH];   // 40 KB: exp(transitions) slice, chunk-padded
  __shared__ float Avec[64 * CH];     // 5 KB: staged scaled input vector
  __shared__ float yrow[RPW];

  const int tid  = threadIdx.x;
  const int lane = tid & 63;
  const int wid  = tid >> 6;
  const int b    = blockIdx.x;
  const bool isFwd = (b < NWG);
  const int g = isFwd ? b : b - NWG;

  // preload W slice (exp domain). fwd: rows [8g,8g+8). bwd: cols [8g,8g+8) (i.e. W^T rows).
  for (int idx = tid; idx < RPW * LLAB; idx += 256) {
    int r = idx >> 10, j = idx & (LLAB - 1);
    float tv = isFwd ? trans[(size_t)(RPW * g + r) * LLAB + j]
                     : trans[(size_t)j * LLAB + (RPW * g + r)];
    W[r][(j >> 4) * CH + (j & 15)] = __expf(tv);   // exp(-10000) flushes to 0: correct
  }

  int*    flags = isFwd ? fwdFlag : bwdFlag;
  float*  vec   = isFwd ? fwdA : bwdV;
  double* sc    = isFwd ? fwdSc : bwdSc;

  // initial publish: state 0 at parity 0.
  // fwd: one-hot at START (label L-2), scale 0. bwd: all-ones, scale -10000 (= trans[STOP] row).
  if (wid == 0) {
    if (lane < RPW) {
      float v0 = isFwd ? ((RPW * g + lane == LLAB - 2) ? 1.0f : 0.0f) : 1.0f;
      __hip_atomic_store(&vec[RPW * g + lane], v0, __ATOMIC_RELAXED, __HIP_MEMORY_SCOPE_AGENT);
    }
    if (lane == 0) {
      __hip_atomic_store(&sc[g], isFwd ? 0.0 : -10000.0, __ATOMIC_RELAXED, __HIP_MEMORY_SCOPE_AGENT);
      __hip_atomic_store(&flags[g], 1, __ATOMIC_RELEASE, __HIP_MEMORY_SCOPE_AGENT);
    }
  }
  __syncthreads();

  double m_cons = 0.0;  // consumed-scale max, lives in wave0 registers across phases

  for (int n = 0; n < HALF; ++n) {
    const int pin = n & 1, pout = pin ^ 1;

    // ---- phase A (wave 0): poll flags, load + rescale input vector into LDS ----
    if (wid == 0) {
      const int want = n + 1;
      for (;;) {
        int fa = __hip_atomic_load(&flags[2 * lane],     __ATOMIC_ACQUIRE, __HIP_MEMORY_SCOPE_AGENT);
        int fb = __hip_atomic_load(&flags[2 * lane + 1], __ATOMIC_ACQUIRE, __HIP_MEMORY_SCOPE_AGENT);
        if (__all(fa >= want && fb >= want)) break;
      }
      double s0 = __hip_atomic_load(&sc[pin * NWG + 2 * lane],     __ATOMIC_RELAXED, __HIP_MEMORY_SCOPE_AGENT);
      double s1 = __hip_atomic_load(&sc[pin * NWG + 2 * lane + 1], __ATOMIC_RELAXED, __HIP_MEMORY_SCOPE_AGENT);
      float av[16];
      const float* src = vec + pin * LLAB + 16 * lane;
#pragma unroll
      for (int k = 0; k < 16; ++k)
        av[k] = __hip_atomic_load(src + k, __ATOMIC_RELAXED, __HIP_MEMORY_SCOPE_AGENT);
      double m = fmax(s0, s1);
#pragma unroll
      for (int off = 32; off >= 1; off >>= 1) m = fmax(m, __shfl_xor(m, off));
      float f0 = __expf((float)(s0 - m));
      float f1 = __expf((float)(s1 - m));
      if (!isFwd) {  // backward applies diag(exp(feat_t)) on the input side, t = T-1-n
        const float* fr = pred + (size_t)(TT - 1 - n) * LLAB + 16 * lane;
#pragma unroll
        for (int k = 0; k < 16; ++k) av[k] *= __expf(fr[k]);
      }
#pragma unroll
      for (int k = 0; k < 16; ++k)
        Avec[lane * CH + k] = av[k] * (k < 8 ? f0 : f1);
      m_cons = m;
    }
    __syncthreads();

    // ---- phase B (all 4 waves): 2 dot-products of length 1024 per wave ----
    {
      const int r0 = 2 * wid, r1 = r0 + 1;
      const float4* A4 = (const float4*)&Avec[lane * CH];
      const float4* W0 = (const float4*)&W[r0][lane * CH];
      const float4* W1 = (const float4*)&W[r1][lane * CH];
      float p0 = 0.f, p1 = 0.f;
#pragma unroll
      for (int q = 0; q < 4; ++q) {
        float4 a = A4[q], w0 = W0[q], w1 = W1[q];
        p0 = fmaf(w0.x, a.x, p0); p0 = fmaf(w0.y, a.y, p0);
        p0 = fmaf(w0.z, a.z, p0); p0 = fmaf(w0.w, a.w, p0);
        p1 = fmaf(w1.x, a.x, p1); p1 = fmaf(w1.y, a.y, p1);
        p1 = fmaf(w1.z, a.z, p1); p1 = fmaf(w1.w, a.w, p1);
      }
#pragma unroll
      for (int off = 32; off >= 1; off >>= 1) {
        p0 += __shfl_xor(p0, off);
        p1 += __shfl_xor(p1, off);
      }
      if (lane == 0) { yrow[r0] = p0; yrow[r1] = p1; }
    }
    __syncthreads();

    // ---- phase C (wave 0): output-side scaling, normalize, publish ----
    if (wid == 0) {
      float z = 0.f;
      if (lane < RPW) {
        float y = yrow[lane];
        z = isFwd ? y * __expf(pred[(size_t)n * LLAB + RPW * g + lane]) : y;
      }
      float zm = z;  // lanes >= RPW contribute 0; slice max is provably > 0
#pragma unroll
      for (int off = 32; off >= 1; off >>= 1) zm = fmaxf(zm, __shfl_xor(zm, off));
      if (lane < RPW)
        __hip_atomic_store(&vec[pout * LLAB + RPW * g + lane], z / zm,
                           __ATOMIC_RELAXED, __HIP_MEMORY_SCOPE_AGENT);
      if (lane == 0) {
        __hip_atomic_store(&sc[pout * NWG + g], m_cons + (double)__logf(zm),
                           __ATOMIC_RELAXED, __HIP_MEMORY_SCOPE_AGENT);
        __hip_atomic_store(&flags[g], n + 2, __ATOMIC_RELEASE, __HIP_MEMORY_SCOPE_AGENT);
      }
    }
  }
}

// ---------------- final combine: score = log(v_half . a_half) - gold ----------------
__global__ __launch_bounds__(256) void crf_final(
    const float* __restrict__ fwdA, const float* __restrict__ bwdV,
    const double* __restrict__ fwdSc, const double* __restrict__ bwdSc,
    const float* __restrict__ gold, float* __restrict__ out) {
  int tid = threadIdx.x;
  double w[4]; double mx = -1e300;
#pragma unroll
  for (int q = 0; q < 4; ++q) {
    int i = q * 256 + tid;
    float af = fwdA[i], bv = bwdV[i];   // parity-0 buffers hold the half-point states
    double ww = -1e300;
    if (af > 0.f && bv > 0.f)
      ww = (double)__logf(af) + (double)__logf(bv) + fwdSc[i >> 3] + bwdSc[i >> 3];
    w[q] = ww; mx = fmax(mx, ww);
  }
#pragma unroll
  for (int off = 32; off >= 1; off >>= 1) mx = fmax(mx, __shfl_xor(mx, off));
  __shared__ double sm[4];
  if ((tid & 63) == 0) sm[tid >> 6] = mx;
  __syncthreads();
  double gmx = fmax(fmax(sm[0], sm[1]), fmax(sm[2], sm[3]));
  double s = 0.0;
#pragma unroll
  for (int q = 0; q < 4; ++q) s += exp(w[q] - gmx);
#pragma unroll
  for (int off = 32; off >= 1; off >>= 1) s += __shfl_xor(s, off);
  __shared__ double ssum[4];
  if ((tid & 63) == 0) ssum[tid >> 6] = s;
  __syncthreads();
  if (tid == 0) {
    double fs = gmx + log(ssum[0] + ssum[1] + ssum[2] + ssum[3]);
    out[0] = (float)(fs - (double)gold[0]);
  }
}

extern "C" void kernel_launch(void* const* d_in, const int* in_sizes, int n_in,
                              void* d_out, int out_size, void* d_ws, size_t ws_size,
                              hipStream_t stream) {
  const float* pred  = (const float*)d_in[0];   // (16384, 1024) f32
  const int*   ref   = (const int*)d_in[1];     // (16384,) i32
  const float* trans = (const float*)d_in[2];   // (1024, 1024) f32
  float* out = (float*)d_out;

  char* ws = (char*)d_ws;
  int*    fwdFlag = (int*)(ws + 0);        // 128 ints
  int*    bwdFlag = (int*)(ws + 512);      // 128 ints
  float*  gold    = (float*)(ws + 1024);   // 1 float
  float*  fwdA    = (float*)(ws + 2048);   // [2][1024] f32
  float*  bwdV    = (float*)(ws + 10240);  // [2][1024] f32
  double* fwdSc   = (double*)(ws + 18432); // [2][128] f64
  double* bwdSc   = (double*)(ws + 20480); // [2][128] f64

  hipMemsetAsync(ws, 0, 2048, stream);  // zero flags + gold accumulator
  crf_gold<<<64, 256, 0, stream>>>(pred, ref, trans, gold);
  crf_persistent<<<2 * NWG, 256, 0, stream>>>(pred, trans, fwdFlag, bwdFlag,
                                              fwdA, bwdV, fwdSc, bwdSc);
  crf_final<<<1, 256, 0, stream>>>(fwdA, bwdV, fwdSc, bwdSc, gold, out);
}

// Round 2
// 73852.325 us; speedup vs baseline: 1.4459x; 1.4459x over previous
//
#include <hip/hip_runtime.h>

// CRF loss, T=16384, L=1024, exp-domain meet-in-the-middle dataflow.
// v2: 64 fwd + 64 bwd persistent wgs (1/CU). Each wg owns 16 rows of W=exp(trans)
// (fwd) or W^T (bwd) ENTIRELY IN REGISTERS (4 rows x 16 cols per lane = 64 VGPRs).
// Per step: relaxed-poll 64 flags (1/lane, 64B-padded) -> one acquire fence ->
// load vec (relaxed 8B atomics) -> 64 reg-FMAs -> butterfly reduce -> one barrier ->
// wave0 normalizes + publishes 16 floats + scale, release fence, flag++.
// pred row prefetched before the poll (flag-independent).

#define TT    16384
#define LLAB  1024
#define HALF  8192
#define NWG   64     // workgroups per direction
#define ROWS  16     // rows per workgroup
#define RPWV  4      // rows per wave
#define FPAD  16     // flag/scale padding stride in dwords (64 B)
#define AGT   __HIP_MEMORY_SCOPE_AGENT

// ---------------- gold path score ----------------
__global__ __launch_bounds__(256) void crf_gold(const float* __restrict__ pred,
                                                const int* __restrict__ ref,
                                                const float* __restrict__ trans,
                                                float* __restrict__ gold) {
  int t = blockIdx.x * 256 + threadIdx.x;           // grid 64 -> one t per thread
  int r = ref[t];
  int prev = (t == 0) ? (LLAB - 2) : ref[t - 1];    // START = L-2
  float v = trans[(size_t)r * LLAB + prev] + pred[(size_t)t * LLAB + r];
  if (t == TT - 1) v += trans[(size_t)(LLAB - 1) * LLAB + r];  // STOP row (= -10000)
#pragma unroll
  for (int off = 32; off >= 1; off >>= 1) v += __shfl_xor(v, off);
  __shared__ float acc[4];
  if ((threadIdx.x & 63) == 0) acc[threadIdx.x >> 6] = v;
  __syncthreads();
  if (threadIdx.x == 0) atomicAdd(gold, acc[0] + acc[1] + acc[2] + acc[3]);
}

// ---------------- persistent dataflow kernel ----------------
__global__ __launch_bounds__(256) void crf_persistent(
    const float* __restrict__ pred, const float* __restrict__ trans,
    int* __restrict__ flagF, int* __restrict__ flagB,
    float* __restrict__ vecF, float* __restrict__ vecB,
    float* __restrict__ scF, float* __restrict__ scB) {
  __shared__ float yrowL[ROWS];

  const int tid  = threadIdx.x;
  const int lane = tid & 63;
  const int wid  = tid >> 6;
  const bool isFwd = (blockIdx.x < NWG);
  const int g  = isFwd ? (int)blockIdx.x : (int)blockIdx.x - NWG;
  const int r0 = ROWS * g;

  int*   flags = isFwd ? flagF : flagB;
  float* vec   = isFwd ? vecF : vecB;
  float* sc    = isFwd ? scF  : scB;

  // W fragment in registers: rows r0+4*wid+q, cols 16*lane+k (bwd: W^T).
  float wreg[RPWV][16];
#pragma unroll
  for (int q = 0; q < RPWV; ++q) {
    const int gr = r0 + RPWV * wid + q;
#pragma unroll
    for (int k = 0; k < 16; ++k) {
      const int col = 16 * lane + k;
      float tv = isFwd ? trans[(size_t)gr * LLAB + col]
                       : trans[(size_t)col * LLAB + gr];
      wreg[q][k] = __expf(tv);   // exp(-10000) -> 0: START/STOP rows die correctly
    }
  }

  // initial publish: parity 0, flag = 1.
  // fwd: one-hot at START (L-2), scale 0. bwd: ones, scale -10000 (trans[STOP] row is const NEG).
  if (wid == 0) {
    if (lane < ROWS) {
      float v0 = isFwd ? ((r0 + lane == LLAB - 2) ? 1.0f : 0.0f) : 1.0f;
      __hip_atomic_store(&vec[r0 + lane], v0, __ATOMIC_RELAXED, AGT);
    }
    if (lane == 0)
      __hip_atomic_store(&sc[g * FPAD], isFwd ? 0.0f : -10000.0f, __ATOMIC_RELAXED, AGT);
    __builtin_amdgcn_fence(__ATOMIC_RELEASE, "agent");
    if (lane == 0)
      __hip_atomic_store(&flags[g * FPAD], 1, __ATOMIC_RELAXED, AGT);
  }

  for (int n = 0; n < HALF; ++n) {
    const int pin = n & 1, pout = pin ^ 1;

    // ---- prefetch pred (independent of flags, hides HBM/LLC latency under poll) ----
    float4 pa, pb, pc, pd;
    if (isFwd) {
      pa = *(const float4*)&pred[(size_t)n * LLAB + r0 + RPWV * wid];
      pb = pc = pd = pa;
    } else {
      const float4* pp = (const float4*)&pred[(size_t)(TT - 1 - n) * LLAB + 16 * lane];
      pa = pp[0]; pb = pp[1]; pc = pp[2]; pd = pp[3];
    }

    // ---- poll: relaxed loads, one flag per lane; single acquire fence on success ----
    {
      const int want = n + 1;
      for (;;) {
        int fl = __hip_atomic_load(&flags[lane * FPAD], __ATOMIC_RELAXED, AGT);
        if (__all(fl >= want)) break;
      }
      __builtin_amdgcn_fence(__ATOMIC_ACQUIRE, "agent");
    }

    // ---- consume: per-slice scale (slice s covers elements [16s,16s+16)) ----
    float s = __hip_atomic_load(&sc[(pin * NWG + lane) * FPAD], __ATOMIC_RELAXED, AGT);
    float m = s;
#pragma unroll
    for (int off = 32; off >= 1; off >>= 1) m = fmaxf(m, __shfl_xor(m, off));
    const float fsc = __expf(s - m);

    // vec elements [16*lane, 16*lane+16) via 8-byte relaxed atomic loads (always fresh)
    float av[16];
    {
      const unsigned long long* vp =
          (const unsigned long long*)&vec[pin * LLAB + 16 * lane];
#pragma unroll
      for (int h = 0; h < 8; ++h) {
        unsigned long long u = __hip_atomic_load(vp + h, __ATOMIC_RELAXED, AGT);
        union { unsigned long long u; float f[2]; } cvt; cvt.u = u;
        av[2 * h] = cvt.f[0]; av[2 * h + 1] = cvt.f[1];
      }
    }
    if (!isFwd) {  // backward applies diag(exp(feat_t)) on the input side
      float pe[16] = {pa.x, pa.y, pa.z, pa.w, pb.x, pb.y, pb.z, pb.w,
                      pc.x, pc.y, pc.z, pc.w, pd.x, pd.y, pd.z, pd.w};
#pragma unroll
      for (int k = 0; k < 16; ++k) av[k] *= __expf(pe[k]);
    }
#pragma unroll
    for (int k = 0; k < 16; ++k) av[k] *= fsc;

    // ---- 4 rows x 16 cols of register FMAs, butterfly-reduce 4 sums ----
    float p[RPWV];
#pragma unroll
    for (int q = 0; q < RPWV; ++q) {
      float acc = 0.f;
#pragma unroll
      for (int k = 0; k < 16; ++k) acc = fmaf(wreg[q][k], av[k], acc);
      p[q] = acc;
    }
#pragma unroll
    for (int off = 32; off >= 1; off >>= 1) {
#pragma unroll
      for (int q = 0; q < RPWV; ++q) p[q] += __shfl_xor(p[q], off);
    }
    if (lane == 0) {
      if (isFwd) {  // forward applies emission on the output side
        p[0] *= __expf(pa.x); p[1] *= __expf(pa.y);
        p[2] *= __expf(pa.z); p[3] *= __expf(pa.w);
      }
      yrowL[RPWV * wid + 0] = p[0]; yrowL[RPWV * wid + 1] = p[1];
      yrowL[RPWV * wid + 2] = p[2]; yrowL[RPWV * wid + 3] = p[3];
    }
    __syncthreads();  // the ONLY barrier per step (own-flag handshake covers the rest)

    // ---- wave0: normalize slice, publish, release, advance flag ----
    if (wid == 0) {
      float z = yrowL[lane & (ROWS - 1)];
      float zm = z;
#pragma unroll
      for (int off = 32; off >= 1; off >>= 1) zm = fmaxf(zm, __shfl_xor(zm, off));
      if (lane < ROWS)
        __hip_atomic_store(&vec[pout * LLAB + r0 + lane], z / zm, __ATOMIC_RELAXED, AGT);
      if (lane == 0)
        __hip_atomic_store(&sc[(pout * NWG + g) * FPAD], m + __logf(zm),
                           __ATOMIC_RELAXED, AGT);
      __builtin_amdgcn_fence(__ATOMIC_RELEASE, "agent");
      if (lane == 0)
        __hip_atomic_store(&flags[g * FPAD], n + 2, __ATOMIC_RELAXED, AGT);
    }
  }
}

// ---------------- final combine: score = log(fwd . bwd) - gold ----------------
__global__ __launch_bounds__(256) void crf_final(
    const float* __restrict__ fwdA, const float* __restrict__ bwdV,
    const float* __restrict__ scF, const float* __restrict__ scB,
    const float* __restrict__ gold, float* __restrict__ out) {
  int tid = threadIdx.x;
  double w[4]; double mx = -1e300;
#pragma unroll
  for (int q = 0; q < 4; ++q) {
    int i = q * 256 + tid;
    float af = fwdA[i], bv = bwdV[i];   // parity-0 buffers hold the half-point states
    double ww = -1e300;
    if (af > 0.f && bv > 0.f)
      ww = (double)__logf(af) + (double)__logf(bv) +
           (double)scF[(i >> 4) * FPAD] + (double)scB[(i >> 4) * FPAD];
    w[q] = ww; mx = fmax(mx, ww);
  }
#pragma unroll
  for (int off = 32; off >= 1; off >>= 1) mx = fmax(mx, __shfl_xor(mx, off));
  __shared__ double sm[4];
  if ((tid & 63) == 0) sm[tid >> 6] = mx;
  __syncthreads();
  double gmx = fmax(fmax(sm[0], sm[1]), fmax(sm[2], sm[3]));
  double s = 0.0;
#pragma unroll
  for (int q = 0; q < 4; ++q) s += exp(w[q] - gmx);
#pragma unroll
  for (int off = 32; off >= 1; off >>= 1) s += __shfl_xor(s, off);
  __shared__ double ssum[4];
  if ((tid & 63) == 0) ssum[tid >> 6] = s;
  __syncthreads();
  if (tid == 0) {
    double fs = gmx + log(ssum[0] + ssum[1] + ssum[2] + ssum[3]);
    out[0] = (float)(fs - (double)gold[0]);
  }
}

extern "C" void kernel_launch(void* const* d_in, const int* in_sizes, int n_in,
                              void* d_out, int out_size, void* d_ws, size_t ws_size,
                              hipStream_t stream) {
  const float* pred  = (const float*)d_in[0];   // (16384, 1024) f32
  const int*   ref   = (const int*)d_in[1];     // (16384,) i32
  const float* trans = (const float*)d_in[2];   // (1024, 1024) f32
  float* out = (float*)d_out;

  char* ws = (char*)d_ws;
  int*   flagF = (int*)(ws + 0);        // 64 flags, 64B stride = 4096 B
  int*   flagB = (int*)(ws + 4096);     // 4096 B
  float* gold  = (float*)(ws + 8192);   // 256 B slot
  float* vecF  = (float*)(ws + 8448);   // [2][1024] f32 = 8192 B
  float* vecB  = (float*)(ws + 16640);  // 8192 B
  float* scF   = (float*)(ws + 24832);  // [2][64*16] f32 = 8192 B
  float* scB   = (float*)(ws + 33024);  // 8192 B

  hipMemsetAsync(ws, 0, 8448, stream);  // zero flags + gold accumulator
  crf_gold<<<64, 256, 0, stream>>>(pred, ref, trans, gold);
  crf_persistent<<<2 * NWG, 256, 0, stream>>>(pred, trans, flagF, flagB,
                                              vecF, vecB, scF, scB);
  crf_final<<<1, 256, 0, stream>>>(vecF, vecB, scF, scB, gold, out);
}

// Round 3
// 40611.795 us; speedup vs baseline: 2.6294x; 1.8185x over previous
//
#include <hip/hip_runtime.h>

// CRF loss, T=16384, L=1024. v3: fence-free seqlock dataflow.
// Exp-domain recurrence split fwd/bwd (meet in the middle). 128 slices/direction,
// 8 rows per slice, ONE WAVE per slice, W fragment in 128 VGPRs. Publications are
// 64-bit words [tag:32 | bf16 | bf16] via relaxed agent atomics: tag+payload are one
// atomic quantum -> NO fences, NO barriers, NO LDS. Each wave checks 16 tag words
// whose union (across its 64 lanes) covers all 128 producers -> implicit global
// barrier per step -> 2-parity ring buffer is race-free.

#define TT   16384
#define LLAB 1024
#define HALF 8192
#define NSL  128   // slices (waves) per direction
#define RPS  8     // rows per slice
#define AGT  __HIP_MEMORY_SCOPE_AGENT

typedef unsigned long long u64;
typedef unsigned int u32;

__device__ __forceinline__ u32 f2bf(float f) {   // RTN f32 -> bf16 bits
  u32 u = __builtin_bit_cast(u32, f);
  return (u + 0x7FFFu + ((u >> 16) & 1u)) >> 16;
}
__device__ __forceinline__ float bf2f(u32 b) {
  return __builtin_bit_cast(float, b << 16);
}

// ---------------- gold path score ----------------
__global__ __launch_bounds__(256) void crf_gold(const float* __restrict__ pred,
                                                const int* __restrict__ ref,
                                                const float* __restrict__ trans,
                                                float* __restrict__ gold) {
  int t = blockIdx.x * 256 + threadIdx.x;
  int r = ref[t];
  int prev = (t == 0) ? (LLAB - 2) : ref[t - 1];    // START = L-2
  float v = trans[(size_t)r * LLAB + prev] + pred[(size_t)t * LLAB + r];
  if (t == TT - 1) v += trans[(size_t)(LLAB - 1) * LLAB + r];  // STOP row
#pragma unroll
  for (int off = 32; off >= 1; off >>= 1) v += __shfl_xor(v, off);
  __shared__ float acc[4];
  if ((threadIdx.x & 63) == 0) acc[threadIdx.x >> 6] = v;
  __syncthreads();
  if (threadIdx.x == 0) atomicAdd(gold, acc[0] + acc[1] + acc[2] + acc[3]);
}

// ---------------- persistent wave-autonomous dataflow ----------------
// vec[dir]: [2 parity][512] u64  (word i = cols {2i,2i+1})
// sc [dir]: [2 parity][128*8] u64 (slice s at offset s*8: one 64B line per slice)
__global__ __launch_bounds__(256) void crf_persistent(
    const float* __restrict__ pred, const float* __restrict__ trans,
    u64* __restrict__ vecF, u64* __restrict__ vecB,
    u64* __restrict__ scF, u64* __restrict__ scB) {
  const int lane = threadIdx.x & 63;
  const int wid  = threadIdx.x >> 6;
  const int gw   = blockIdx.x * 4 + wid;          // 0..255
  const bool isFwd = (gw < NSL);
  const int s  = gw & (NSL - 1);
  const int r0 = RPS * s;

  u64* vec = isFwd ? vecF : vecB;
  u64* sc  = isFwd ? scF  : scB;

  // W fragment: rows r0..r0+8, cols {2*lane+128j, 2*lane+1+128j} (bwd: W^T)
  float wreg[RPS][16];
#pragma unroll
  for (int q = 0; q < RPS; ++q) {
#pragma unroll
    for (int j = 0; j < 8; ++j) {
      const int c = 2 * lane + 128 * j;
      float t0, t1;
      if (isFwd) {
        t0 = trans[(size_t)(r0 + q) * LLAB + c];
        t1 = trans[(size_t)(r0 + q) * LLAB + c + 1];
      } else {
        t0 = trans[(size_t)c * LLAB + (r0 + q)];
        t1 = trans[(size_t)(c + 1) * LLAB + (r0 + q)];
      }
      wreg[q][2 * j]     = __expf(t0);  // exp(-10000) -> 0: START/STOP die correctly
      wreg[q][2 * j + 1] = __expf(t1);
    }
  }

  // ---- initial publish (parity 0, tag 1), lane 0 of each wave ----
  if (lane == 0) {
    const u64 tag1 = (u64)1u << 32;
    if (isFwd) {  // one-hot at START (col 1022), scale 0
#pragma unroll
      for (int h = 0; h < 4; ++h) {
        u32 b0 = (r0 + 2 * h     == LLAB - 2) ? 0x3F80u : 0u;
        u32 b1 = (r0 + 2 * h + 1 == LLAB - 2) ? 0x3F80u : 0u;
        __hip_atomic_store(&vec[4 * s + h], tag1 | ((u64)b1 << 16) | b0,
                           __ATOMIC_RELAXED, AGT);
      }
      __hip_atomic_store(&sc[s * 8], tag1 | __builtin_bit_cast(u32, 0.0f),
                         __ATOMIC_RELAXED, AGT);
    } else {      // u0 = exp(pred[T-1]) ⊙ ones, overall scale -10000 (STOP row)
      float e[RPS], zm = 0.f;
#pragma unroll
      for (int q = 0; q < RPS; ++q) {
        e[q] = __expf(pred[(size_t)(TT - 1) * LLAB + r0 + q]);
        zm = fmaxf(zm, e[q]);
      }
      float inv = 1.0f / zm;
#pragma unroll
      for (int h = 0; h < 4; ++h)
        __hip_atomic_store(&vec[4 * s + h],
                           tag1 | ((u64)f2bf(e[2 * h + 1] * inv) << 16) | f2bf(e[2 * h] * inv),
                           __ATOMIC_RELAXED, AGT);
      float scv = -10000.0f + __logf(zm);
      __hip_atomic_store(&sc[s * 8], tag1 | __builtin_bit_cast(u32, scv),
                         __ATOMIC_RELAXED, AGT);
    }
  }

  // ---- main loop: one implicit global barrier per step via seqlock tags ----
  for (int n = 0; n < HALF; ++n) {
    const int pin = n & 1, pout = pin ^ 1;
    const u32 want = (u32)(n + 1);

    // pred prefetch: own 8 rows' emissions (fwd: row n; bwd: row T-2-n, output side)
    float4 e0, e1;
    {
      const int t = isFwd ? n : (TT - 2 - n);   // bwd n==HALF-1 loads row 8191, unused
      const float4* ep = (const float4*)&pred[(size_t)t * LLAB + r0];
      e0 = ep[0]; e1 = ep[1];
    }

    const u64* vin = vec + (size_t)pin * 512;
    const u64* sin = sc  + (size_t)pin * 1024;
    u64 dw[8], sw[8];
    for (;;) {
#pragma unroll
      for (int j = 0; j < 8; ++j)
        dw[j] = __hip_atomic_load(&vin[lane + 64 * j], __ATOMIC_RELAXED, AGT);
#pragma unroll
      for (int j = 0; j < 8; ++j)
        sw[j] = __hip_atomic_load(&sin[(lane / 4 + 16 * j) * 8], __ATOMIC_RELAXED, AGT);
      bool ok = true;
#pragma unroll
      for (int j = 0; j < 8; ++j)
        ok = ok && ((u32)(dw[j] >> 32) == want) && ((u32)(sw[j] >> 32) == want);
      if (__all(ok)) break;
    }

    // per-slice scales -> common max m, factors
    float sv[8], m = -1e30f;
#pragma unroll
    for (int j = 0; j < 8; ++j) {
      sv[j] = __builtin_bit_cast(float, (u32)sw[j]);
      m = fmaxf(m, sv[j]);
    }
#pragma unroll
    for (int off = 32; off >= 1; off >>= 1) m = fmaxf(m, __shfl_xor(m, off));

    float av[16];
#pragma unroll
    for (int j = 0; j < 8; ++j) {
      const float f = __expf(sv[j] - m);
      av[2 * j]     = bf2f((u32)(dw[j] & 0xFFFFu)) * f;
      av[2 * j + 1] = bf2f((u32)((dw[j] >> 16) & 0xFFFFu)) * f;
    }

    // 8 rows x 16 cols register FMAs, butterfly-reduce
    float p[RPS];
#pragma unroll
    for (int q = 0; q < RPS; ++q) {
      float a = 0.f;
#pragma unroll
      for (int k = 0; k < 16; ++k) a = fmaf(wreg[q][k], av[k], a);
      p[q] = a;
    }
#pragma unroll
    for (int off = 32; off >= 1; off >>= 1) {
#pragma unroll
      for (int q = 0; q < RPS; ++q) p[q] += __shfl_xor(p[q], off);
    }

    // lane 0: emissions (fwd: row n; bwd: row T-2-n except last step), normalize, publish
    if (lane == 0) {
      float em[RPS] = {e0.x, e0.y, e0.z, e0.w, e1.x, e1.y, e1.z, e1.w};
      const bool applyEm = isFwd || (n < HALF - 1);
      if (applyEm) {
#pragma unroll
        for (int q = 0; q < RPS; ++q) p[q] *= __expf(em[q]);
      }
      float zm = 0.f;
#pragma unroll
      for (int q = 0; q < RPS; ++q) zm = fmaxf(zm, p[q]);
      const float inv = 1.0f / zm;
      const u64 tag = (u64)(u32)(n + 2) << 32;
      u64* vout = vec + (size_t)pout * 512;
#pragma unroll
      for (int h = 0; h < 4; ++h)
        __hip_atomic_store(&vout[4 * s + h],
                           tag | ((u64)f2bf(p[2 * h + 1] * inv) << 16) | f2bf(p[2 * h] * inv),
                           __ATOMIC_RELAXED, AGT);
      const float scv = m + __logf(zm);
      __hip_atomic_store(&sc[(size_t)pout * 1024 + s * 8],
                         tag | __builtin_bit_cast(u32, scv), __ATOMIC_RELAXED, AGT);
    }
  }
}

// ---------------- final combine: score = log(a . b) - gold ----------------
__global__ __launch_bounds__(256) void crf_final(
    const u64* __restrict__ vecF, const u64* __restrict__ vecB,
    const u64* __restrict__ scF, const u64* __restrict__ scB,
    const float* __restrict__ gold, float* __restrict__ out) {
  int tid = threadIdx.x;
  double w[4]; double mx = -1e300;
#pragma unroll
  for (int q = 0; q < 4; ++q) {
    int c = q * 256 + tid;
    u64 wa = __hip_atomic_load(&vecF[c >> 1], __ATOMIC_RELAXED, AGT);
    u64 wb = __hip_atomic_load(&vecB[c >> 1], __ATOMIC_RELAXED, AGT);
    u32 ba = (c & 1) ? (u32)((wa >> 16) & 0xFFFFu) : (u32)(wa & 0xFFFFu);
    u32 bb = (c & 1) ? (u32)((wb >> 16) & 0xFFFFu) : (u32)(wb & 0xFFFFu);
    float af = bf2f(ba), bv = bf2f(bb);
    u64 sa = __hip_atomic_load(&scF[(c >> 3) * 8], __ATOMIC_RELAXED, AGT);
    u64 sb = __hip_atomic_load(&scB[(c >> 3) * 8], __ATOMIC_RELAXED, AGT);
    double ww = -1e300;
    if (af > 0.f && bv > 0.f)
      ww = (double)__logf(af) + (double)__logf(bv) +
           (double)__builtin_bit_cast(float, (u32)sa) +
           (double)__builtin_bit_cast(float, (u32)sb);
    w[q] = ww; mx = fmax(mx, ww);
  }
#pragma unroll
  for (int off = 32; off >= 1; off >>= 1) mx = fmax(mx, __shfl_xor(mx, off));
  __shared__ double sm[4];
  if ((tid & 63) == 0) sm[tid >> 6] = mx;
  __syncthreads();
  double gmx = fmax(fmax(sm[0], sm[1]), fmax(sm[2], sm[3]));
  double ssum = 0.0;
#pragma unroll
  for (int q = 0; q < 4; ++q) ssum += exp(w[q] - gmx);
#pragma unroll
  for (int off = 32; off >= 1; off >>= 1) ssum += __shfl_xor(ssum, off);
  __shared__ double sd[4];
  if ((tid & 63) == 0) sd[tid >> 6] = ssum;
  __syncthreads();
  if (tid == 0) {
    double fs = gmx + log(sd[0] + sd[1] + sd[2] + sd[3]);
    out[0] = (float)(fs - (double)gold[0]);
  }
}

extern "C" void kernel_launch(void* const* d_in, const int* in_sizes, int n_in,
                              void* d_out, int out_size, void* d_ws, size_t ws_size,
                              hipStream_t stream) {
  const float* pred  = (const float*)d_in[0];   // (16384, 1024) f32
  const int*   ref   = (const int*)d_in[1];     // (16384,) i32
  const float* trans = (const float*)d_in[2];   // (1024, 1024) f32
  float* out = (float*)d_out;

  char* ws = (char*)d_ws;
  float* gold = (float*)(ws + 0);          // 4 B (memset 256)
  u64* vecF = (u64*)(ws + 256);            // [2][512]  u64 = 8192 B
  u64* vecB = (u64*)(ws + 8448);           // 8192 B
  u64* scF  = (u64*)(ws + 16640);          // [2][1024] u64 = 16384 B
  u64* scB  = (u64*)(ws + 33024);          // 16384 B -> end 49408 B

  hipMemsetAsync(ws, 0, 256, stream);      // zero gold accumulator
  crf_gold<<<64, 256, 0, stream>>>(pred, ref, trans, gold);
  crf_persistent<<<64, 256, 0, stream>>>(pred, trans, vecF, vecB, scF, scB);
  crf_final<<<1, 256, 0, stream>>>(vecF, vecB, scF, scB, gold, out);
}

// Round 7
// 27155.130 us; speedup vs baseline: 3.9325x; 1.4955x over previous
//
#include <hip/hip_runtime.h>

// CRF loss, T=16384, L=1024. v7: v3's PROVEN transport (compiler-generated
// agent-scope relaxed u64 atomic loads/stores — no inline asm, the common factor
// in all three failed rounds) + v6's packed record layout.
// 128 fwd + 128 bwd wave-autonomous slices (8 rows each, W=exp(trans) in VGPRs).
// Per step each slice publishes ONE 32-byte record = 4 self-tagged u64 words
// (16-bit tag; scale embedded in word 0). Consumer lane l polls slices 2l,2l+1 =
// 64 contiguous bytes (one cache line) with per-lane done-mask quenching.
// No fences, no barriers, no LDS, no XCD assumptions.

#define TT   16384
#define LLAB 1024
#define HALF 8192
#define NSL  128   // slices per direction
#define RPS  8     // rows per slice
#define AGT  __HIP_MEMORY_SCOPE_AGENT

typedef unsigned long long u64;
typedef unsigned int u32;

__device__ __forceinline__ u32 f2bf(float f) {   // RTN f32 -> bf16 bits
  u32 u = __builtin_bit_cast(u32, f);
  return (u + 0x7FFFu + ((u >> 16) & 1u)) >> 16;
}
__device__ __forceinline__ float bf2f(u32 b) {
  return __builtin_bit_cast(float, b << 16);
}
__device__ __forceinline__ void pub(u64* p, u64 v) {
  __hip_atomic_store(p, v, __ATOMIC_RELAXED, AGT);
}
__device__ __forceinline__ u64 aload(const u64* p) {
  return __hip_atomic_load(p, __ATOMIC_RELAXED, AGT);
}
// Record: w0 = [scale_f32:63..32 | 0 | tag:15..0]
//         w1 = [b0:63..48 | b1:47..32 | b2:31..16 | tag]
//         w2 = [b3 | b4 | b5 | tag],  w3 = [b6 | b7 | 0 | tag]

// ---------------- gold path score ----------------
__global__ __launch_bounds__(256) void crf_gold(const float* __restrict__ pred,
                                                const int* __restrict__ ref,
                                                const float* __restrict__ trans,
                                                float* __restrict__ gold) {
  int t = blockIdx.x * 256 + threadIdx.x;
  int r = ref[t];
  int prev = (t == 0) ? (LLAB - 2) : ref[t - 1];    // START = L-2
  float v = trans[(size_t)r * LLAB + prev] + pred[(size_t)t * LLAB + r];
  if (t == TT - 1) v += trans[(size_t)(LLAB - 1) * LLAB + r];  // STOP row
#pragma unroll
  for (int off = 32; off >= 1; off >>= 1) v += __shfl_xor(v, off);
  __shared__ float acc[4];
  if ((threadIdx.x & 63) == 0) acc[threadIdx.x >> 6] = v;
  __syncthreads();
  if (threadIdx.x == 0) atomicAdd(gold, acc[0] + acc[1] + acc[2] + acc[3]);
}

// ---------------- persistent wave-autonomous dataflow ----------------
// rec[dir]: [2 parity][128 slices][4 u64] = 8 KB
__global__ __launch_bounds__(256) void crf_persistent(
    const float* __restrict__ pred, const float* __restrict__ trans,
    u64* __restrict__ recF, u64* __restrict__ recB) {
  const int lane = threadIdx.x & 63;
  const int wid  = threadIdx.x >> 6;
  const int gw   = blockIdx.x * 4 + wid;          // 0..255
  const bool isFwd = (gw < NSL);
  const int s  = gw & (NSL - 1);
  const int r0 = RPS * s;

  u64* rec = isFwd ? recF : recB;

  // ---- W fragment in VGPRs: rows r0..r0+8, cols [16*lane, 16*lane+16) (bwd: W^T)
  float wreg[RPS][16];
#pragma unroll
  for (int q = 0; q < RPS; ++q) {
    if (isFwd) {
      const float4* tp = (const float4*)&trans[(size_t)(r0 + q) * LLAB + 16 * lane];
      float4 t0 = tp[0], t1 = tp[1], t2 = tp[2], t3 = tp[3];
      float tv[16] = {t0.x, t0.y, t0.z, t0.w, t1.x, t1.y, t1.z, t1.w,
                      t2.x, t2.y, t2.z, t2.w, t3.x, t3.y, t3.z, t3.w};
#pragma unroll
      for (int k = 0; k < 16; ++k) wreg[q][k] = __expf(tv[k]);
    } else {
#pragma unroll
      for (int k = 0; k < 16; ++k)
        wreg[q][k] = __expf(trans[(size_t)(16 * lane + k) * LLAB + (r0 + q)]);
    }
  }

  // ---- initial publish (parity 0, tag 1), lane 0 of each wave
  if (lane == 0) {
    const u64 tag1 = 1;
    u32 b[RPS];
    float scv;
    if (isFwd) {  // one-hot at START (label 1022), scale 0
#pragma unroll
      for (int q = 0; q < RPS; ++q) b[q] = (r0 + q == LLAB - 2) ? 0x3F80u : 0u;
      scv = 0.0f;
    } else {      // u0 = exp(pred[T-1]) normalized; scale -10000 + log zm
      float e[RPS], zm = 0.f;
#pragma unroll
      for (int q = 0; q < RPS; ++q) {
        e[q] = __expf(pred[(size_t)(TT - 1) * LLAB + r0 + q]);
        zm = fmaxf(zm, e[q]);
      }
      float inv = 1.0f / zm;
#pragma unroll
      for (int q = 0; q < RPS; ++q) b[q] = f2bf(e[q] * inv);
      scv = -10000.0f + __logf(zm);
    }
    u64* rp = rec + 4 * s;
    pub(&rp[0], ((u64)__builtin_bit_cast(u32, scv) << 32) | tag1);
    pub(&rp[1], ((u64)b[0] << 48) | ((u64)b[1] << 32) | ((u64)b[2] << 16) | tag1);
    pub(&rp[2], ((u64)b[3] << 48) | ((u64)b[4] << 32) | ((u64)b[5] << 16) | tag1);
    pub(&rp[3], ((u64)b[6] << 48) | ((u64)b[7] << 32) | tag1);
  }

  // ---- main loop ----
  for (int n = 0; n < HALF; ++n) {
    const int pin = n & 1, pout = pin ^ 1;
    const u64 want = (u64)(u32)(n + 1) & 0xFFFFu;

    // pred prefetch (flag-independent): own 8 rows' emissions
    float4 e0, e1;
    {
      const int t = isFwd ? n : (TT - 2 - n);   // bwd n==HALF-1 row unused
      const float4* ep = (const float4*)&pred[(size_t)t * LLAB + r0];
      e0 = ep[0]; e1 = ep[1];
    }

    // poll: lane l needs slices 2l, 2l+1 = 64 contiguous bytes (1 cache line)
    const u64* rp = rec + pin * 512 + 8 * lane;
    u64 w[8];
    bool done = false;
    do {
      if (!done) {
#pragma unroll
        for (int j = 0; j < 8; ++j) w[j] = aload(rp + j);
        bool ok = true;
#pragma unroll
        for (int j = 0; j < 8; ++j) ok = ok && ((w[j] & 0xFFFFu) == want);
        done = ok;
      }
    } while (!__all(done));

    // scales -> global max m, per-slice factors
    const float sv0 = __builtin_bit_cast(float, (u32)(w[0] >> 32));
    const float sv1 = __builtin_bit_cast(float, (u32)(w[4] >> 32));
    float m = fmaxf(sv0, sv1);
#pragma unroll
    for (int off = 32; off >= 1; off >>= 1) m = fmaxf(m, __shfl_xor(m, off));
    const float f0 = __expf(sv0 - m), f1 = __expf(sv1 - m);

    // unpack 16 bf16 values: w[1..3] = slice 2l (cols 16l..16l+7), w[5..7] = 2l+1
    float av[16];
#pragma unroll
    for (int h = 0; h < 2; ++h) {
      const float f = h ? f1 : f0;
      const u64 x1 = w[4 * h + 1], x2 = w[4 * h + 2], x3 = w[4 * h + 3];
      av[8 * h + 0] = bf2f((u32)(x1 >> 48)) * f;
      av[8 * h + 1] = bf2f((u32)(x1 >> 32) & 0xFFFFu) * f;
      av[8 * h + 2] = bf2f((u32)(x1 >> 16) & 0xFFFFu) * f;
      av[8 * h + 3] = bf2f((u32)(x2 >> 48)) * f;
      av[8 * h + 4] = bf2f((u32)(x2 >> 32) & 0xFFFFu) * f;
      av[8 * h + 5] = bf2f((u32)(x2 >> 16) & 0xFFFFu) * f;
      av[8 * h + 6] = bf2f((u32)(x3 >> 48)) * f;
      av[8 * h + 7] = bf2f((u32)(x3 >> 32) & 0xFFFFu) * f;
    }

    // 8 rows x 16 cols register FMAs, butterfly-reduce
    float p[RPS];
#pragma unroll
    for (int q = 0; q < RPS; ++q) {
      float acc = 0.f;
#pragma unroll
      for (int k = 0; k < 16; ++k) acc = fmaf(wreg[q][k], av[k], acc);
      p[q] = acc;
    }
#pragma unroll
    for (int off = 32; off >= 1; off >>= 1) {
#pragma unroll
      for (int q = 0; q < RPS; ++q) p[q] += __shfl_xor(p[q], off);
    }

    // lane 0: emissions (bwd skips on last step), normalize, publish record
    if (lane == 0) {
      float em[RPS] = {e0.x, e0.y, e0.z, e0.w, e1.x, e1.y, e1.z, e1.w};
      if (isFwd || (n < HALF - 1)) {
#pragma unroll
        for (int q = 0; q < RPS; ++q) p[q] *= __expf(em[q]);
      }
      float zm = 0.f;
#pragma unroll
      for (int q = 0; q < RPS; ++q) zm = fmaxf(zm, p[q]);
      const float inv = 1.0f / zm;
      u32 b[RPS];
#pragma unroll
      for (int q = 0; q < RPS; ++q) b[q] = f2bf(p[q] * inv);
      const u64 tag = (u64)(u32)(n + 2) & 0xFFFFu;
      const float scv = m + __logf(zm);
      u64* ro = rec + pout * 512 + 4 * s;
      pub(&ro[0], ((u64)__builtin_bit_cast(u32, scv) << 32) | tag);
      pub(&ro[1], ((u64)b[0] << 48) | ((u64)b[1] << 32) | ((u64)b[2] << 16) | tag);
      pub(&ro[2], ((u64)b[3] << 48) | ((u64)b[4] << 32) | ((u64)b[5] << 16) | tag);
      pub(&ro[3], ((u64)b[6] << 48) | ((u64)b[7] << 32) | tag);
    }
  }
}

// ---------------- final combine: score = log(a . b) - gold ----------------
__global__ __launch_bounds__(256) void crf_final(
    const u64* __restrict__ recF, const u64* __restrict__ recB,
    const float* __restrict__ gold, float* __restrict__ out) {
  const int tid = threadIdx.x;
  double w[4]; double mx = -1e300;
#pragma unroll
  for (int q = 0; q < 4; ++q) {
    int c = q * 256 + tid;
    int sl = c >> 3, j = c & 7;
    const u64* ra = recF + 4 * sl;   // parity 0 = final states
    const u64* rb = recB + 4 * sl;
    u64 wa = ra[1 + j / 3], wb = rb[1 + j / 3];
    int sh = 48 - 16 * (j % 3);
    float af = bf2f((u32)((wa >> sh) & 0xFFFFu));
    float bv = bf2f((u32)((wb >> sh) & 0xFFFFu));
    double ww = -1e300;
    if (af > 0.f && bv > 0.f)
      ww = (double)__logf(af) + (double)__logf(bv) +
           (double)__builtin_bit_cast(float, (u32)(ra[0] >> 32)) +
           (double)__builtin_bit_cast(float, (u32)(rb[0] >> 32));
    w[q] = ww; mx = fmax(mx, ww);
  }
#pragma unroll
  for (int off = 32; off >= 1; off >>= 1) mx = fmax(mx, __shfl_xor(mx, off));
  __shared__ double sm[4];
  if ((tid & 63) == 0) sm[tid >> 6] = mx;
  __syncthreads();
  double gmx = fmax(fmax(sm[0], sm[1]), fmax(sm[2], sm[3]));
  double ssum = 0.0;
#pragma unroll
  for (int q = 0; q < 4; ++q) ssum += exp(w[q] - gmx);
#pragma unroll
  for (int off = 32; off >= 1; off >>= 1) ssum += __shfl_xor(ssum, off);
  __shared__ double sd[4];
  if ((tid & 63) == 0) sd[tid >> 6] = ssum;
  __syncthreads();
  if (tid == 0) {
    double fs = gmx + log(sd[0] + sd[1] + sd[2] + sd[3]);
    out[0] = (float)(fs - (double)gold[0]);
  }
}

extern "C" void kernel_launch(void* const* d_in, const int* in_sizes, int n_in,
                              void* d_out, int out_size, void* d_ws, size_t ws_size,
                              hipStream_t stream) {
  const float* pred  = (const float*)d_in[0];   // (16384, 1024) f32
  const int*   ref   = (const int*)d_in[1];     // (16384,) i32
  const float* trans = (const float*)d_in[2];   // (1024, 1024) f32
  float* out = (float*)d_out;

  char* ws = (char*)d_ws;
  float* gold = (float*)(ws + 0);     // 4 B (memset 256)
  u64* recF = (u64*)(ws + 256);       // [2][128][4] u64 = 8192 B
  u64* recB = (u64*)(ws + 8448);      // 8192 B -> end 16640 B

  hipMemsetAsync(ws, 0, 256, stream); // zero gold accumulator
  crf_gold<<<64, 256, 0, stream>>>(pred, ref, trans, gold);
  crf_persistent<<<64, 256, 0, stream>>>(pred, trans, recF, recB);
  crf_final<<<1, 256, 0, stream>>>(recF, recB, gold, out);
}

// Round 8
// 26488.513 us; speedup vs baseline: 4.0314x; 1.0252x over previous
//
#include <hip/hip_runtime.h>

// CRF loss, T=16384, L=1024. v8: v7's proven seqlock protocol, restructured to cut
// MALL transaction pressure ~6x. 64 slices x 16 rows per direction (128 waves).
// Record = 64B-aligned: 6 self-tagged u64 words [payload:48|tag:16]:
//   w0 = [scale f32 | v0 f16 | tag], w1..w5 = [3x f16 | tag].
// Lane l owns slice l: spins on w0 ONLY (1 atomic load/sweep/lane), then bulk-reads
// w1..w5 (self-tagged, published simultaneously by a 6-lane store). W held as
// packed f16 pairs (v_dot2_f32_f16, __has_builtin-guarded). Emission exps computed
// in the post-publish idle window from flag-independent prefetches.
// fwd: emission rows 0..8191 output-side; bwd: rows 16383..8192 input-side.

#define TT   16384
#define LLAB 1024
#define HALF 8192
#define NSL  64    // slices per direction
#define RPS  16    // rows per slice
#define AGT  __HIP_MEMORY_SCOPE_AGENT

typedef unsigned long long u64;
typedef unsigned int u32;
typedef unsigned short u16;
typedef _Float16 h2 __attribute__((ext_vector_type(2)));

__device__ __forceinline__ void pub(u64* p, u64 v) {
  __hip_atomic_store(p, v, __ATOMIC_RELAXED, AGT);
}
__device__ __forceinline__ u64 aload(const u64* p) {
  return __hip_atomic_load(p, __ATOMIC_RELAXED, AGT);
}
__device__ __forceinline__ u32 pack2(float a, float b) {
  h2 h = {(_Float16)a, (_Float16)b};
  return __builtin_bit_cast(u32, h);
}
__device__ __forceinline__ u32 f16bits(float x) {
  return (u32)__builtin_bit_cast(u16, (_Float16)x);
}
__device__ __forceinline__ float f16val(u32 b) {
  return (float)__builtin_bit_cast(_Float16, (u16)b);
}
#if __has_builtin(__builtin_amdgcn_fdot2)
__device__ __forceinline__ float dot2(u32 w, u32 a, float c) {
  return __builtin_amdgcn_fdot2(__builtin_bit_cast(h2, w),
                                __builtin_bit_cast(h2, a), c, false);
}
#else
__device__ __forceinline__ float dot2(u32 w, u32 a, float c) {
  h2 hw = __builtin_bit_cast(h2, w), ha = __builtin_bit_cast(h2, a);
  return c + (float)hw[0] * (float)ha[0] + (float)hw[1] * (float)ha[1];
}
#endif

// ---------------- gold path score ----------------
__global__ __launch_bounds__(256) void crf_gold(const float* __restrict__ pred,
                                                const int* __restrict__ ref,
                                                const float* __restrict__ trans,
                                                float* __restrict__ gold) {
  int t = blockIdx.x * 256 + threadIdx.x;
  int r = ref[t];
  int prev = (t == 0) ? (LLAB - 2) : ref[t - 1];    // START = L-2
  float v = trans[(size_t)r * LLAB + prev] + pred[(size_t)t * LLAB + r];
  if (t == TT - 1) v += trans[(size_t)(LLAB - 1) * LLAB + r];  // STOP row
#pragma unroll
  for (int off = 32; off >= 1; off >>= 1) v += __shfl_xor(v, off);
  __shared__ float acc[4];
  if ((threadIdx.x & 63) == 0) acc[threadIdx.x >> 6] = v;
  __syncthreads();
  if (threadIdx.x == 0) atomicAdd(gold, acc[0] + acc[1] + acc[2] + acc[3]);
}

// ---------------- persistent wave-autonomous dataflow ----------------
// rec[dir]: [2 parity][64 slices][8 u64] = 8 KB each
__global__ __launch_bounds__(256) void crf_persistent(
    const float* __restrict__ pred, const float* __restrict__ trans,
    u64* __restrict__ recF, u64* __restrict__ recB) {
  const int lane = threadIdx.x & 63;
  const int wid  = threadIdx.x >> 6;
  const int gw   = blockIdx.x * 4 + wid;          // 0..127
  const bool isFwd = (gw < NSL);
  const int s  = gw & (NSL - 1);
  const int r0 = RPS * s;
  u64* rec = isFwd ? recF : recB;

  // ---- W as packed f16 pairs: rows r0+q, col pair (32 per lane... 16 cols/lane)
  u32 wpk[RPS][8];
#pragma unroll
  for (int q = 0; q < RPS; ++q) {
    if (isFwd) {
      const float4* tp = (const float4*)&trans[(size_t)(r0 + q) * LLAB + 16 * lane];
      float4 t0 = tp[0], t1 = tp[1], t2 = tp[2], t3 = tp[3];
      wpk[q][0] = pack2(__expf(t0.x), __expf(t0.y));
      wpk[q][1] = pack2(__expf(t0.z), __expf(t0.w));
      wpk[q][2] = pack2(__expf(t1.x), __expf(t1.y));
      wpk[q][3] = pack2(__expf(t1.z), __expf(t1.w));
      wpk[q][4] = pack2(__expf(t2.x), __expf(t2.y));
      wpk[q][5] = pack2(__expf(t2.z), __expf(t2.w));
      wpk[q][6] = pack2(__expf(t3.x), __expf(t3.y));
      wpk[q][7] = pack2(__expf(t3.z), __expf(t3.w));
    } else {
#pragma unroll
      for (int j = 0; j < 8; ++j) {
        float a = trans[(size_t)(16 * lane + 2 * j) * LLAB + (r0 + q)];
        float b = trans[(size_t)(16 * lane + 2 * j + 1) * LLAB + (r0 + q)];
        wpk[q][j] = pack2(__expf(a), __expf(b));
      }
    }
  }

  // ---- initial publish (parity 0, tag 1), 6-lane parallel store
  if (lane < 6) {
    const u64 tg = 1;
    u64 w;
    if (isFwd) {  // one-hot at col 1022 = slice 63, pos 14 (word 5, shift 32); scale 0
      u64 w0 = ((u64)__builtin_bit_cast(u32, 0.0f) << 32) | tg;
      u64 w5 = (s == 63) ? (((u64)0x3C00u << 32) | tg) : tg;
      w = (lane == 0) ? w0 : (lane == 5) ? w5 : tg;
    } else {      // B0 = exp(trans[STOP,:]) = const: ones payload, scale -10000
      u64 w0 = ((u64)__builtin_bit_cast(u32, -10000.0f) << 32) | ((u64)0x3C00u << 16) | tg;
      u64 wj = ((u64)0x3C00u << 48) | ((u64)0x3C00u << 32) | ((u64)0x3C00u << 16) | tg;
      w = (lane == 0) ? w0 : wj;
    }
    pub(rec + s * 8 + lane, w);
  }

  // ---- prefetch emission row for step 0, compute exps
  float4 pa, pb, pc, pd;
  {
    const float* ep = isFwd ? &pred[0 * LLAB + r0]
                            : &pred[(size_t)(TT - 1) * LLAB + 16 * lane];
    const float4* e4 = (const float4*)ep;
    pa = e4[0]; pb = e4[1]; pc = e4[2]; pd = e4[3];
  }
  float femo[RPS];   // fwd: output-side, broadcast, f32
  u32 fempk[8];      // bwd: input-side, per-lane, packed f16
  {
    float f[16] = {pa.x, pa.y, pa.z, pa.w, pb.x, pb.y, pb.z, pb.w,
                   pc.x, pc.y, pc.z, pc.w, pd.x, pd.y, pd.z, pd.w};
    if (isFwd) {
#pragma unroll
      for (int i = 0; i < 16; ++i) femo[i] = __expf(f[i]);
    } else {
#pragma unroll
      for (int j = 0; j < 8; ++j) fempk[j] = pack2(__expf(f[2 * j]), __expf(f[2 * j + 1]));
    }
  }

  // ---- main loop ----
  for (int n = 0; n < HALF; ++n) {
    const int pin = n & 1, pout = pin ^ 1;
    const u32 want = (u32)(n + 1);
    const u64* rp = rec + pin * 512 + lane * 8;

    // spin on w0 only (1 atomic load per sweep per lane), done-quench
    u64 w0;
    {
      bool done = false;
      do {
        if (!done) {
          w0 = aload(rp);
          done = ((u32)(w0 & 0xFFFFu) == want);
        }
      } while (!__all(done));
    }
    // bulk-read w1..w5 (self-tagged; published simultaneously -> retry ~never)
    u64 wd[5];
    {
      bool d2 = false;
      do {
        if (!d2) {
#pragma unroll
          for (int j = 0; j < 5; ++j) wd[j] = aload(rp + 1 + j);
          bool ok = true;
#pragma unroll
          for (int j = 0; j < 5; ++j) ok = ok && ((u32)(wd[j] & 0xFFFFu) == want);
          d2 = ok;
        }
      } while (!__all(d2));
    }

    // issue flag-independent prefetch of next step's emission row
    {
      const int t = isFwd ? (n + 1) : (TT - 2 - n);
      const float* ep = isFwd ? &pred[(size_t)t * LLAB + r0]
                              : &pred[(size_t)t * LLAB + 16 * lane];
      const float4* e4 = (const float4*)ep;
      pa = e4[0]; pb = e4[1]; pc = e4[2]; pd = e4[3];
    }

    // per-slice scale -> global max m, lane factor
    const float sv = __builtin_bit_cast(float, (u32)(w0 >> 32));
    float m = sv;
#pragma unroll
    for (int off = 32; off >= 1; off >>= 1) m = fmaxf(m, __shfl_xor(m, off));
    const float fl = __expf(sv - m);

    // unpack 16 f16 values -> 8 packed pairs; bwd folds input-side emissions
    u32 v[16];
    v[0] = (u32)(w0 >> 16) & 0xFFFFu;
#pragma unroll
    for (int jw = 0; jw < 5; ++jw) {
      v[3 * jw + 1] = (u32)(wd[jw] >> 48);
      v[3 * jw + 2] = (u32)(wd[jw] >> 32) & 0xFFFFu;
      v[3 * jw + 3] = (u32)(wd[jw] >> 16) & 0xFFFFu;
    }
    u32 apk[8];
#pragma unroll
    for (int j = 0; j < 8; ++j) apk[j] = v[2 * j] | (v[2 * j + 1] << 16);
    if (!isFwd) {
#pragma unroll
      for (int j = 0; j < 8; ++j) {
        h2 prod = __builtin_bit_cast(h2, apk[j]) * __builtin_bit_cast(h2, fempk[j]);
        apk[j] = __builtin_bit_cast(u32, prod);
      }
    }

    // 16 rows x 8 dot2 each, scale by lane factor, butterfly allreduce
    float p[RPS];
#pragma unroll
    for (int q = 0; q < RPS; ++q) {
      float a = 0.f;
#pragma unroll
      for (int j = 0; j < 8; ++j) a = dot2(wpk[q][j], apk[j], a);
      p[q] = a * fl;
    }
#pragma unroll
    for (int off = 32; off >= 1; off >>= 1) {
#pragma unroll
      for (int q = 0; q < RPS; ++q) p[q] += __shfl_xor(p[q], off);
    }

    // fwd: output-side emission; normalize; pack; 6-lane parallel publish
    float z[RPS];
#pragma unroll
    for (int q = 0; q < RPS; ++q) z[q] = isFwd ? p[q] * femo[q] : p[q];
    float zm = 0.f;
#pragma unroll
    for (int q = 0; q < RPS; ++q) zm = fmaxf(zm, z[q]);
    const float inv = 1.0f / zm;
    u32 zh[RPS];
#pragma unroll
    for (int q = 0; q < RPS; ++q) zh[q] = f16bits(z[q] * inv);
    const u64 tg = (u64)(u32)(n + 2);
    const float scn = m + __logf(zm);
    u64 p0 = ((u64)__builtin_bit_cast(u32, scn) << 32) | ((u64)zh[0] << 16) | tg;
    u64 p1 = ((u64)zh[1] << 48) | ((u64)zh[2] << 32) | ((u64)zh[3] << 16) | tg;
    u64 p2 = ((u64)zh[4] << 48) | ((u64)zh[5] << 32) | ((u64)zh[6] << 16) | tg;
    u64 p3 = ((u64)zh[7] << 48) | ((u64)zh[8] << 32) | ((u64)zh[9] << 16) | tg;
    u64 p4 = ((u64)zh[10] << 48) | ((u64)zh[11] << 32) | ((u64)zh[12] << 16) | tg;
    u64 p5 = ((u64)zh[13] << 48) | ((u64)zh[14] << 32) | ((u64)zh[15] << 16) | tg;
    u64 wsel = p0;
    wsel = (lane == 1) ? p1 : wsel;
    wsel = (lane == 2) ? p2 : wsel;
    wsel = (lane == 3) ? p3 : wsel;
    wsel = (lane == 4) ? p4 : wsel;
    wsel = (lane == 5) ? p5 : wsel;
    if (lane < 6) pub(rec + pout * 512 + s * 8 + lane, wsel);

    // idle window: compute next step's emission exps from the prefetch
    {
      float f[16] = {pa.x, pa.y, pa.z, pa.w, pb.x, pb.y, pb.z, pb.w,
                     pc.x, pc.y, pc.z, pc.w, pd.x, pd.y, pd.z, pd.w};
      if (isFwd) {
#pragma unroll
        for (int i = 0; i < 16; ++i) femo[i] = __expf(f[i]);
      } else {
#pragma unroll
        for (int j = 0; j < 8; ++j) fempk[j] = pack2(__expf(f[2 * j]), __expf(f[2 * j + 1]));
      }
    }
  }
}

// ---------------- final combine: score = log(F . B) - gold ----------------
__global__ __launch_bounds__(256) void crf_final(
    const u64* __restrict__ recF, const u64* __restrict__ recB,
    const float* __restrict__ gold, float* __restrict__ out) {
  const int tid = threadIdx.x;
  double w[4]; double mx = -1e300;
#pragma unroll
  for (int q = 0; q < 4; ++q) {
    int c = q * 256 + tid;
    int sl = c >> 4, pos = c & 15;
    const u64* ra = recF + 8 * sl;   // parity 0 = final states (step 8192)
    const u64* rb = recB + 8 * sl;
    u32 ba, bb;
    if (pos == 0) {
      ba = (u32)(ra[0] >> 16) & 0xFFFFu;
      bb = (u32)(rb[0] >> 16) & 0xFFFFu;
    } else {
      int wi = 1 + (pos - 1) / 3, sh = 48 - 16 * ((pos - 1) % 3);
      ba = (u32)(ra[wi] >> sh) & 0xFFFFu;
      bb = (u32)(rb[wi] >> sh) & 0xFFFFu;
    }
    float af = f16val(ba), bv = f16val(bb);
    double ww = -1e300;
    if (af > 0.f && bv > 0.f)
      ww = log((double)af) + log((double)bv) +
           (double)__builtin_bit_cast(float, (u32)(ra[0] >> 32)) +
           (double)__builtin_bit_cast(float, (u32)(rb[0] >> 32));
    w[q] = ww; mx = fmax(mx, ww);
  }
#pragma unroll
  for (int off = 32; off >= 1; off >>= 1) mx = fmax(mx, __shfl_xor(mx, off));
  __shared__ double sm[4];
  if ((tid & 63) == 0) sm[tid >> 6] = mx;
  __syncthreads();
  double gmx = fmax(fmax(sm[0], sm[1]), fmax(sm[2], sm[3]));
  double ssum = 0.0;
#pragma unroll
  for (int q = 0; q < 4; ++q) ssum += exp(w[q] - gmx);
#pragma unroll
  for (int off = 32; off >= 1; off >>= 1) ssum += __shfl_xor(ssum, off);
  __shared__ double sd[4];
  if ((tid & 63) == 0) sd[tid >> 6] = ssum;
  __syncthreads();
  if (tid == 0) {
    double fs = gmx + log(sd[0] + sd[1] + sd[2] + sd[3]);
    out[0] = (float)(fs - (double)gold[0]);
  }
}

extern "C" void kernel_launch(void* const* d_in, const int* in_sizes, int n_in,
                              void* d_out, int out_size, void* d_ws, size_t ws_size,
                              hipStream_t stream) {
  const float* pred  = (const float*)d_in[0];   // (16384, 1024) f32
  const int*   ref   = (const int*)d_in[1];     // (16384,) i32
  const float* trans = (const float*)d_in[2];   // (1024, 1024) f32
  float* out = (float*)d_out;

  char* ws = (char*)d_ws;
  float* gold = (float*)(ws + 0);     // 4 B (memset 256)
  u64* recF = (u64*)(ws + 256);       // [2][64][8] u64 = 8192 B
  u64* recB = (u64*)(ws + 8448);      // 8192 B -> end 16640 B

  hipMemsetAsync(ws, 0, 256, stream); // zero gold accumulator
  crf_gold<<<64, 256, 0, stream>>>(pred, ref, trans, gold);
  crf_persistent<<<32, 256, 0, stream>>>(pred, trans, recF, recB);
  crf_final<<<1, 256, 0, stream>>>(recF, recB, gold, out);
}